// Round 1
// baseline (880.152 us; speedup 1.0000x reference)
//
#include <hip/hip_runtime.h>
#include <hip/hip_bf16.h>

typedef __bf16 bf16_t;
typedef __bf16 bf16x8 __attribute__((ext_vector_type(8)));
typedef __bf16 bf16x4 __attribute__((ext_vector_type(4)));
typedef float f32x4 __attribute__((ext_vector_type(4)));

#define T_TOK 4096
#define DIM   1024
#define HID   2048
#define NE    8
#define LDK   72   // padded LDS K-stride (elements); 72*2=144B keeps 16B align for b128

// ---------------- x -> bf16 ----------------
__global__ __launch_bounds__(256) void k_xconv(const float* __restrict__ x,
                                               bf16_t* __restrict__ xb) {
  int i = (blockIdx.x * 256 + threadIdx.x) * 4;
  float4 v = *(const float4*)(x + i);
  bf16x4 o;
  o[0] = (bf16_t)v.x; o[1] = (bf16_t)v.y; o[2] = (bf16_t)v.z; o[3] = (bf16_t)v.w;
  *(bf16x4*)(xb + i) = o;
}

// ---------------- router: logits, sigmoid, top-2, aux ----------------
__global__ __launch_bounds__(256) void k_router(const float* __restrict__ x,
    const float* __restrict__ rw, const float* __restrict__ rb,
    int* __restrict__ counts, int* __restrict__ top_i, float* __restrict__ top_w,
    float* __restrict__ aux) {
  int t = blockIdx.x * 4 + (threadIdx.x >> 6);
  int lane = threadIdx.x & 63;
  const float* xt = x + (size_t)t * DIM;
  float acc[8] = {0.f,0.f,0.f,0.f,0.f,0.f,0.f,0.f};
  for (int i = lane; i < DIM; i += 64) {
    float xv = xt[i];
    float4 r0 = *(const float4*)(rw + i * 8);
    float4 r1 = *(const float4*)(rw + i * 8 + 4);
    acc[0] += xv * r0.x; acc[1] += xv * r0.y; acc[2] += xv * r0.z; acc[3] += xv * r0.w;
    acc[4] += xv * r1.x; acc[5] += xv * r1.y; acc[6] += xv * r1.z; acc[7] += xv * r1.w;
  }
#pragma unroll
  for (int m = 32; m >= 1; m >>= 1) {
#pragma unroll
    for (int e = 0; e < 8; ++e) acc[e] += __shfl_xor(acc[e], m, 64);
  }
  if (lane == 0) {
    float s[8]; float sumsq = 0.f;
#pragma unroll
    for (int e = 0; e < 8; ++e) {
      float lg = acc[e] + rb[e];
      sumsq += lg * lg;
      s[e] = 1.f / (1.f + __expf(-lg));
    }
    int i1 = 0;
#pragma unroll
    for (int e = 1; e < 8; ++e) if (s[e] > s[i1]) i1 = e;      // ties -> lower idx
    int i2 = (i1 == 0) ? 1 : 0;
#pragma unroll
    for (int e = 0; e < 8; ++e) if (e != i1 && s[e] > s[i2]) i2 = e;
    float v1 = s[i1], v2 = s[i2];
    float den = v1 + v2 + 1e-6f;
    top_i[2 * t]     = i1; top_i[2 * t + 1] = i2;
    top_w[2 * t]     = v1 / den;
    top_w[2 * t + 1] = v2 / den;
    atomicAdd(&counts[i1], 1);
    atomicAdd(&counts[i2], 1);
    atomicAdd(aux, 0.01f * sumsq * (1.f / 32768.f));
  }
}

// ---------------- exclusive scan over 8 counts ----------------
__global__ void k_scan(const int* __restrict__ counts, int* __restrict__ base) {
  if (threadIdx.x == 0) {
    int s = 0;
    for (int e = 0; e < 8; ++e) { base[e] = s; s += counts[e]; }
  }
}

// ---------------- gather tokens into per-expert slot lists ----------------
__global__ __launch_bounds__(256) void k_gather(const int* __restrict__ top_i,
    const float* __restrict__ top_w, const int* __restrict__ base,
    int* __restrict__ fill, int* __restrict__ slot_token, float* __restrict__ slot_wt) {
  int t = blockIdx.x * 256 + threadIdx.x;
  if (t >= T_TOK) return;
#pragma unroll
  for (int j = 0; j < 2; ++j) {
    int e = top_i[2 * t + j];
    int p = atomicAdd(&fill[e], 1);
    int g = base[e] + p;
    slot_token[g] = t;
    slot_wt[g]    = top_w[2 * t + j];
  }
}

// ---------------- GEMM1 + SwiGLU: h = silu(X@W1) * (X@W2) ----------------
// tile: 128 rows x 64 h-cols (two 64-wide x12 panels). 4 waves (2x2).
__global__ __launch_bounds__(256) void k_gemm1(
    const bf16_t* __restrict__ xb, const float* __restrict__ w12,
    const int* __restrict__ counts, const int* __restrict__ base,
    const int* __restrict__ slot_token, bf16_t* __restrict__ h) {
  const int e   = blockIdx.z;
  const int cnt = counts[e];
  const int m0  = blockIdx.y * 128;
  if (m0 >= cnt) return;
  const int n0  = blockIdx.x * 64;
  const int bas = base[e];
  const float* W = w12 + (size_t)e * DIM * (2 * HID);

  __shared__ bf16_t sA[128 * LDK];
  __shared__ bf16_t sB1[64 * LDK];
  __shared__ bf16_t sB2[64 * LDK];

  const int tid = threadIdx.x;
  const int lane = tid & 63, wid = tid >> 6;
  const int wr = wid >> 1, wc = wid & 1;

  f32x4 acc1[4][2] = {};
  f32x4 acc2[4][2] = {};

  for (int kt = 0; kt < DIM / 64; ++kt) {
    const int k0 = kt * 64;
    // stage A (gathered tokens, already bf16): 128x64
#pragma unroll
    for (int c = tid; c < 2048; c += 256) {
      int row = c >> 4, col = (c & 15) << 2;
      uint2 v = make_uint2(0u, 0u);
      if (m0 + row < cnt) {
        int tok = slot_token[bas + m0 + row];
        v = *(const uint2*)(xb + (size_t)tok * DIM + k0 + col);
      }
      *(uint2*)(sA + row * LDK + col) = v;
    }
    // stage B panels transposed (w12 is K-outer): LDS holds B^T [n][k]
#pragma unroll
    for (int c = tid; c < 1024; c += 256) {
      int k = c >> 4, n = (c & 15) << 2;
      const float* p1 = W + (size_t)(k0 + k) * (2 * HID) + n0 + n;
      float4 v1 = *(const float4*)p1;
      float4 v2 = *(const float4*)(p1 + HID);
      sB1[(n + 0) * LDK + k] = (bf16_t)v1.x;
      sB1[(n + 1) * LDK + k] = (bf16_t)v1.y;
      sB1[(n + 2) * LDK + k] = (bf16_t)v1.z;
      sB1[(n + 3) * LDK + k] = (bf16_t)v1.w;
      sB2[(n + 0) * LDK + k] = (bf16_t)v2.x;
      sB2[(n + 1) * LDK + k] = (bf16_t)v2.y;
      sB2[(n + 2) * LDK + k] = (bf16_t)v2.z;
      sB2[(n + 3) * LDK + k] = (bf16_t)v2.w;
    }
    __syncthreads();
#pragma unroll
    for (int kk = 0; kk < 2; ++kk) {
      const int kb = kk * 32 + ((lane >> 4) << 3);
      bf16x8 a[4], b1[2], b2[2];
#pragma unroll
      for (int mf = 0; mf < 4; ++mf)
        a[mf] = *(const bf16x8*)(sA + (wr * 64 + mf * 16 + (lane & 15)) * LDK + kb);
#pragma unroll
      for (int nf = 0; nf < 2; ++nf) {
        b1[nf] = *(const bf16x8*)(sB1 + (wc * 32 + nf * 16 + (lane & 15)) * LDK + kb);
        b2[nf] = *(const bf16x8*)(sB2 + (wc * 32 + nf * 16 + (lane & 15)) * LDK + kb);
      }
#pragma unroll
      for (int mf = 0; mf < 4; ++mf)
#pragma unroll
        for (int nf = 0; nf < 2; ++nf) {
          acc1[mf][nf] = __builtin_amdgcn_mfma_f32_16x16x32_bf16(a[mf], b1[nf], acc1[mf][nf], 0, 0, 0);
          acc2[mf][nf] = __builtin_amdgcn_mfma_f32_16x16x32_bf16(a[mf], b2[nf], acc2[mf][nf], 0, 0, 0);
        }
    }
    __syncthreads();
  }
  // epilogue: SwiGLU, write h (bf16). C/D: col=lane&15, row=(lane>>4)*4+r
#pragma unroll
  for (int mf = 0; mf < 4; ++mf) {
#pragma unroll
    for (int r = 0; r < 4; ++r) {
      int m = wr * 64 + mf * 16 + ((lane >> 4) << 2) + r;
      if (m0 + m < cnt) {
        size_t rowoff = (size_t)(bas + m0 + m) * HID + n0;
#pragma unroll
        for (int nf = 0; nf < 2; ++nf) {
          int col = wc * 32 + nf * 16 + (lane & 15);
          float d1 = acc1[mf][nf][r], d2 = acc2[mf][nf][r];
          float hv = (d1 / (1.f + __expf(-d1))) * d2;
          h[rowoff + col] = (bf16_t)hv;
        }
      }
    }
  }
}

// ---------------- GEMM2 + scaled scatter: out += wt * (h @ W3) ----------------
__global__ __launch_bounds__(256) void k_gemm2(
    const bf16_t* __restrict__ h, const float* __restrict__ w3,
    const int* __restrict__ counts, const int* __restrict__ base,
    const int* __restrict__ slot_token, const float* __restrict__ slot_wt,
    float* __restrict__ out) {
  const int e   = blockIdx.z;
  const int cnt = counts[e];
  const int m0  = blockIdx.y * 128;
  if (m0 >= cnt) return;
  const int n0  = blockIdx.x * 64;
  const int bas = base[e];
  const float* W = w3 + (size_t)e * HID * DIM;

  __shared__ bf16_t sA[128 * LDK];
  __shared__ bf16_t sB[64 * LDK];

  const int tid = threadIdx.x;
  const int lane = tid & 63, wid = tid >> 6;
  const int wr = wid >> 1, wc = wid & 1;

  f32x4 acc[4][2] = {};

  for (int kt = 0; kt < HID / 64; ++kt) {
    const int k0 = kt * 64;
#pragma unroll
    for (int c = tid; c < 2048; c += 256) {
      int row = c >> 4, col = (c & 15) << 2;
      uint2 v = make_uint2(0u, 0u);
      if (m0 + row < cnt)
        v = *(const uint2*)(h + (size_t)(bas + m0 + row) * HID + k0 + col);
      *(uint2*)(sA + row * LDK + col) = v;
    }
#pragma unroll
    for (int c = tid; c < 1024; c += 256) {
      int k = c >> 4, n = (c & 15) << 2;
      float4 v = *(const float4*)(W + (size_t)(k0 + k) * DIM + n0 + n);
      sB[(n + 0) * LDK + k] = (bf16_t)v.x;
      sB[(n + 1) * LDK + k] = (bf16_t)v.y;
      sB[(n + 2) * LDK + k] = (bf16_t)v.z;
      sB[(n + 3) * LDK + k] = (bf16_t)v.w;
    }
    __syncthreads();
#pragma unroll
    for (int kk = 0; kk < 2; ++kk) {
      const int kb = kk * 32 + ((lane >> 4) << 3);
      bf16x8 a[4], b[2];
#pragma unroll
      for (int mf = 0; mf < 4; ++mf)
        a[mf] = *(const bf16x8*)(sA + (wr * 64 + mf * 16 + (lane & 15)) * LDK + kb);
#pragma unroll
      for (int nf = 0; nf < 2; ++nf)
        b[nf] = *(const bf16x8*)(sB + (wc * 32 + nf * 16 + (lane & 15)) * LDK + kb);
#pragma unroll
      for (int mf = 0; mf < 4; ++mf)
#pragma unroll
        for (int nf = 0; nf < 2; ++nf)
          acc[mf][nf] = __builtin_amdgcn_mfma_f32_16x16x32_bf16(a[mf], b[nf], acc[mf][nf], 0, 0, 0);
    }
    __syncthreads();
  }
#pragma unroll
  for (int mf = 0; mf < 4; ++mf) {
#pragma unroll
    for (int r = 0; r < 4; ++r) {
      int m = wr * 64 + mf * 16 + ((lane >> 4) << 2) + r;
      if (m0 + m < cnt) {
        int g = bas + m0 + m;
        int tok  = slot_token[g];
        float wt = slot_wt[g];
        size_t o = (size_t)tok * DIM + n0;
#pragma unroll
        for (int nf = 0; nf < 2; ++nf) {
          int col = wc * 32 + nf * 16 + (lane & 15);
          atomicAdd(out + o + col, acc[mf][nf][r] * wt);  // exactly 2 adds/elem -> deterministic
        }
      }
    }
  }
}

extern "C" void kernel_launch(void* const* d_in, const int* in_sizes, int n_in,
                              void* d_out, int out_size, void* d_ws, size_t ws_size,
                              hipStream_t stream) {
  const float* x   = (const float*)d_in[0];
  const float* rw  = (const float*)d_in[1];
  const float* rb  = (const float*)d_in[2];
  const float* w12 = (const float*)d_in[3];
  const float* w3  = (const float*)d_in[4];
  float* out = (float*)d_out;

  char* ws = (char*)d_ws;
  // ws layout (total ~40.3 MB)
  int*   counts     = (int*)(ws + 0);        // 8 ints
  int*   fill       = (int*)(ws + 64);       // 8 ints
  int*   base       = (int*)(ws + 128);      // 8 ints
  int*   top_i      = (int*)(ws + 4096);                  // 2*T ints   (32KB)
  float* top_w      = (float*)(ws + 4096 + 32768);        // 2*T floats (32KB)
  int*   slot_token = (int*)(ws + 4096 + 65536);          // 8192 ints  (32KB)
  float* slot_wt    = (float*)(ws + 4096 + 98304);        // 8192 floats(32KB)
  bf16_t* xb        = (bf16_t*)(ws + 262144);             // 4096*1024 bf16 (8MB)
  bf16_t* h         = (bf16_t*)(ws + 262144 + 8388608);   // 8192*2048 bf16 (33.5MB)

  hipMemsetAsync(d_out, 0, (size_t)out_size * sizeof(float), stream); // out + aux accumulators
  hipMemsetAsync(ws, 0, 256, stream);                                 // counts/fill/base

  k_xconv<<<dim3(T_TOK * DIM / 4 / 256), dim3(256), 0, stream>>>(x, xb);
  k_router<<<dim3(T_TOK / 4), dim3(256), 0, stream>>>(x, rw, rb, counts, top_i, top_w,
                                                      out + (size_t)T_TOK * DIM);
  k_scan<<<dim3(1), dim3(64), 0, stream>>>(counts, base);
  k_gather<<<dim3(T_TOK / 256), dim3(256), 0, stream>>>(top_i, top_w, base, fill,
                                                        slot_token, slot_wt);
  k_gemm1<<<dim3(HID / 64, T_TOK / 128, NE), dim3(256), 0, stream>>>(
      xb, w12, counts, base, slot_token, h);
  k_gemm2<<<dim3(DIM / 64, T_TOK / 128, NE), dim3(256), 0, stream>>>(
      h, w3, counts, base, slot_token, slot_wt, out);
}

// Round 3
// 416.750 us; speedup vs baseline: 2.1119x; 2.1119x over previous
//
#include <hip/hip_runtime.h>
#include <hip/hip_bf16.h>
#include <stdint.h>

typedef __bf16 bf16_t;
typedef __bf16 bf16x8 __attribute__((ext_vector_type(8)));
typedef __bf16 bf16x4 __attribute__((ext_vector_type(4)));
typedef float f32x4 __attribute__((ext_vector_type(4)));

#define T_TOK 4096
#define DIM   1024
#define HID   2048
#define NE    8

// async global->LDS, 16B per lane, LDS dest = wave-uniform base + lane*16
__device__ __forceinline__ void gload_lds16(const void* g, void* l) {
  __builtin_amdgcn_global_load_lds(
      (const __attribute__((address_space(1))) unsigned int*)g,
      (__attribute__((address_space(3))) unsigned int*)l, 16, 0, 0);
}

// ---------------- x -> bf16 ----------------
__global__ __launch_bounds__(256) void k_xconv(const float* __restrict__ x,
                                               bf16_t* __restrict__ xb) {
  int i = (blockIdx.x * 256 + threadIdx.x) * 4;
  float4 v = *(const float4*)(x + i);
  bf16x4 o;
  o[0] = (bf16_t)v.x; o[1] = (bf16_t)v.y; o[2] = (bf16_t)v.z; o[3] = (bf16_t)v.w;
  *(bf16x4*)(xb + i) = o;
}

// ---------------- weight transpose+convert: in [K][N] f32 -> out [N][K] bf16 ----------------
__global__ __launch_bounds__(256) void k_wt(const float* __restrict__ in,
                                            bf16_t* __restrict__ out,
                                            int K, int N) {
  __shared__ float tile[64][65];
  const size_t eoff = (size_t)blockIdx.z * K * N;
  const int k0 = blockIdx.y * 64, n0 = blockIdx.x * 64;
  const int tid = threadIdx.x;
#pragma unroll
  for (int it = 0; it < 4; ++it) {
    int k = (tid >> 4) + it * 16;
    int n = (tid & 15) * 4;
    float4 v = *(const float4*)(in + eoff + (size_t)(k0 + k) * N + n0 + n);
    tile[k][n] = v.x; tile[k][n + 1] = v.y; tile[k][n + 2] = v.z; tile[k][n + 3] = v.w;
  }
  __syncthreads();
#pragma unroll
  for (int it = 0; it < 2; ++it) {
    int n = (tid >> 3) + it * 32;
    int kc = (tid & 7) * 8;
    bf16x8 o;
#pragma unroll
    for (int j = 0; j < 8; ++j) o[j] = (bf16_t)tile[kc + j][n];
    *(bf16x8*)(out + eoff + (size_t)(n0 + n) * K + k0 + kc) = o;
  }
}

// ---------------- router: logits, sigmoid, top-2, aux ----------------
__global__ __launch_bounds__(256) void k_router(const float* __restrict__ x,
    const float* __restrict__ rw, const float* __restrict__ rb,
    int* __restrict__ counts, int* __restrict__ top_i, float* __restrict__ top_w,
    float* __restrict__ aux) {
  int t = blockIdx.x * 4 + (threadIdx.x >> 6);
  int lane = threadIdx.x & 63;
  const float* xt = x + (size_t)t * DIM;
  float acc[8] = {0.f,0.f,0.f,0.f,0.f,0.f,0.f,0.f};
  for (int i = lane; i < DIM; i += 64) {
    float xv = xt[i];
    float4 r0 = *(const float4*)(rw + i * 8);
    float4 r1 = *(const float4*)(rw + i * 8 + 4);
    acc[0] += xv * r0.x; acc[1] += xv * r0.y; acc[2] += xv * r0.z; acc[3] += xv * r0.w;
    acc[4] += xv * r1.x; acc[5] += xv * r1.y; acc[6] += xv * r1.z; acc[7] += xv * r1.w;
  }
#pragma unroll
  for (int m = 32; m >= 1; m >>= 1) {
#pragma unroll
    for (int e = 0; e < 8; ++e) acc[e] += __shfl_xor(acc[e], m, 64);
  }
  if (lane == 0) {
    float s[8]; float sumsq = 0.f;
#pragma unroll
    for (int e = 0; e < 8; ++e) {
      float lg = acc[e] + rb[e];
      sumsq += lg * lg;
      s[e] = 1.f / (1.f + __expf(-lg));
    }
    int i1 = 0;
#pragma unroll
    for (int e = 1; e < 8; ++e) if (s[e] > s[i1]) i1 = e;
    int i2 = (i1 == 0) ? 1 : 0;
#pragma unroll
    for (int e = 0; e < 8; ++e) if (e != i1 && s[e] > s[i2]) i2 = e;
    float v1 = s[i1], v2 = s[i2];
    float den = v1 + v2 + 1e-6f;
    top_i[2 * t]     = i1; top_i[2 * t + 1] = i2;
    top_w[2 * t]     = v1 / den;
    top_w[2 * t + 1] = v2 / den;
    atomicAdd(&counts[i1], 1);
    atomicAdd(&counts[i2], 1);
    atomicAdd(aux, 0.01f * sumsq * (1.f / 32768.f));
  }
}

__global__ void k_scan(const int* __restrict__ counts, int* __restrict__ base) {
  if (threadIdx.x == 0) {
    int s = 0;
    for (int e = 0; e < 8; ++e) { base[e] = s; s += counts[e]; }
  }
}

__global__ __launch_bounds__(256) void k_gather(const int* __restrict__ top_i,
    const float* __restrict__ top_w, const int* __restrict__ base,
    int* __restrict__ fill, int* __restrict__ slot_token, float* __restrict__ slot_wt) {
  int t = blockIdx.x * 256 + threadIdx.x;
  if (t >= T_TOK) return;
#pragma unroll
  for (int j = 0; j < 2; ++j) {
    int e = top_i[2 * t + j];
    int p = atomicAdd(&fill[e], 1);
    int g = base[e] + p;
    slot_token[g] = t;
    slot_wt[g]    = top_w[2 * t + j];
  }
}

// ---------------- GEMM1 + SwiGLU ----------------
// tile 128m x 64n (both W1,W2 panels). 4 waves 2x2, wave = 64m x 32n per panel.
// n0 is the HID column base, MUST be in [0, 2048): grid.x = HID/64 = 32.
__global__ __launch_bounds__(256) void k_gemm1(
    const bf16_t* __restrict__ xb, const bf16_t* __restrict__ w12t,
    const int* __restrict__ counts, const int* __restrict__ base,
    const int* __restrict__ slot_token, bf16_t* __restrict__ h) {
  const int e = blockIdx.z;
  const int cnt = counts[e];
  const int m0 = blockIdx.y * 128;
  if (m0 >= cnt) return;
  const int n0 = blockIdx.x * 64;           // hid col base, [0,2048)
  const int bas = base[e];
  const bf16_t* W1 = w12t + (size_t)e * (4096u * 1024u) + (size_t)n0 * 1024u;
  const bf16_t* W2 = W1 + (size_t)2048 * 1024;

  __shared__ bf16_t sA[128 * 64];
  __shared__ bf16_t sB1[64 * 64];
  __shared__ bf16_t sB2[64 * 64];

  const int tid = threadIdx.x, lane = tid & 63, wid = tid >> 6;
  const int wr = wid >> 1, wc = wid & 1;
  const int lr = lane >> 3, sw = (lane & 7) ^ lr;  // swizzled source chunk

  int tokA[4];
#pragma unroll
  for (int i = 0; i < 4; ++i) {
    int row = m0 + wid * 32 + i * 8 + lr;
    tokA[i] = slot_token[bas + (row < cnt ? row : cnt - 1)];
  }

  f32x4 acc1[4][2] = {};
  f32x4 acc2[4][2] = {};

  for (int k0 = 0; k0 < DIM; k0 += 64) {
#pragma unroll
    for (int i = 0; i < 4; ++i)
      gload_lds16(xb + (size_t)tokA[i] * DIM + k0 + sw * 8,
                  sA + (wid * 32 + i * 8) * 64);
#pragma unroll
    for (int i = 0; i < 2; ++i) {
      int n = wid * 16 + i * 8 + lr;
      gload_lds16(W1 + (size_t)n * 1024 + k0 + sw * 8, sB1 + (wid * 16 + i * 8) * 64);
      gload_lds16(W2 + (size_t)n * 1024 + k0 + sw * 8, sB2 + (wid * 16 + i * 8) * 64);
    }
    __syncthreads();
#pragma unroll
    for (int kk = 0; kk < 2; ++kk) {
      const int g = kk * 4 + (lane >> 4);
      bf16x8 a[4], b1[2], b2[2];
#pragma unroll
      for (int mf = 0; mf < 4; ++mf) {
        int r = wr * 64 + mf * 16 + (lane & 15);
        a[mf] = *(const bf16x8*)(sA + r * 64 + ((g ^ (r & 7)) << 3));
      }
#pragma unroll
      for (int nf = 0; nf < 2; ++nf) {
        int n = wc * 32 + nf * 16 + (lane & 15);
        b1[nf] = *(const bf16x8*)(sB1 + n * 64 + ((g ^ (n & 7)) << 3));
        b2[nf] = *(const bf16x8*)(sB2 + n * 64 + ((g ^ (n & 7)) << 3));
      }
#pragma unroll
      for (int mf = 0; mf < 4; ++mf)
#pragma unroll
        for (int nf = 0; nf < 2; ++nf) {
          acc1[mf][nf] = __builtin_amdgcn_mfma_f32_16x16x32_bf16(a[mf], b1[nf], acc1[mf][nf], 0, 0, 0);
          acc2[mf][nf] = __builtin_amdgcn_mfma_f32_16x16x32_bf16(a[mf], b2[nf], acc2[mf][nf], 0, 0, 0);
        }
    }
    __syncthreads();
  }
#pragma unroll
  for (int mf = 0; mf < 4; ++mf)
#pragma unroll
    for (int r = 0; r < 4; ++r) {
      int m = wr * 64 + mf * 16 + ((lane >> 4) << 2) + r;
      if (m0 + m < cnt) {
        size_t rowoff = (size_t)(bas + m0 + m) * HID + n0;
#pragma unroll
        for (int nf = 0; nf < 2; ++nf) {
          int col = wc * 32 + nf * 16 + (lane & 15);
          float d1 = acc1[mf][nf][r], d2 = acc2[mf][nf][r];
          h[rowoff + col] = (bf16_t)((d1 / (1.f + __expf(-d1))) * d2);
        }
      }
    }
}

// ---------------- GEMM2 + scaled scatter ----------------
// tile 128m x 128n, 4 waves 2x2, wave = 64x64. grid.x = DIM/128 = 8.
__global__ __launch_bounds__(256) void k_gemm2(
    const bf16_t* __restrict__ h, const bf16_t* __restrict__ w3t,
    const int* __restrict__ counts, const int* __restrict__ base,
    const int* __restrict__ slot_token, const float* __restrict__ slot_wt,
    float* __restrict__ out) {
  const int e = blockIdx.z;
  const int cnt = counts[e];
  const int m0 = blockIdx.y * 128;
  if (m0 >= cnt) return;
  const int n0 = blockIdx.x * 128;
  const int bas = base[e];
  const bf16_t* W = w3t + (size_t)e * (1024u * 2048u);

  __shared__ bf16_t sA[128 * 64];
  __shared__ bf16_t sB[128 * 64];

  const int tid = threadIdx.x, lane = tid & 63, wid = tid >> 6;
  const int wr = wid >> 1, wc = wid & 1;
  const int lr = lane >> 3, sw = (lane & 7) ^ lr;

  int rowA[4];
#pragma unroll
  for (int i = 0; i < 4; ++i) {
    int row = m0 + wid * 32 + i * 8 + lr;
    rowA[i] = bas + (row < cnt ? row : cnt - 1);
  }

  f32x4 acc[4][4] = {};

  for (int k0 = 0; k0 < HID; k0 += 64) {
#pragma unroll
    for (int i = 0; i < 4; ++i) {
      gload_lds16(h + (size_t)rowA[i] * HID + k0 + sw * 8,
                  sA + (wid * 32 + i * 8) * 64);
      int n = wid * 32 + i * 8 + lr;
      gload_lds16(W + (size_t)(n0 + n) * 2048 + k0 + sw * 8,
                  sB + (wid * 32 + i * 8) * 64);
    }
    __syncthreads();
#pragma unroll
    for (int kk = 0; kk < 2; ++kk) {
      const int g = kk * 4 + (lane >> 4);
      bf16x8 a[4], b[4];
#pragma unroll
      for (int mf = 0; mf < 4; ++mf) {
        int r = wr * 64 + mf * 16 + (lane & 15);
        a[mf] = *(const bf16x8*)(sA + r * 64 + ((g ^ (r & 7)) << 3));
      }
#pragma unroll
      for (int nf = 0; nf < 4; ++nf) {
        int n = wc * 64 + nf * 16 + (lane & 15);
        b[nf] = *(const bf16x8*)(sB + n * 64 + ((g ^ (n & 7)) << 3));
      }
#pragma unroll
      for (int mf = 0; mf < 4; ++mf)
#pragma unroll
        for (int nf = 0; nf < 4; ++nf)
          acc[mf][nf] = __builtin_amdgcn_mfma_f32_16x16x32_bf16(a[mf], b[nf], acc[mf][nf], 0, 0, 0);
    }
    __syncthreads();
  }
#pragma unroll
  for (int mf = 0; mf < 4; ++mf)
#pragma unroll
    for (int r = 0; r < 4; ++r) {
      int m = wr * 64 + mf * 16 + ((lane >> 4) << 2) + r;
      if (m0 + m < cnt) {
        int gs = bas + m0 + m;
        int tok = slot_token[gs];
        float wt = slot_wt[gs];
        size_t o = (size_t)tok * DIM + n0;
#pragma unroll
        for (int nf = 0; nf < 4; ++nf) {
          int col = wc * 64 + nf * 16 + (lane & 15);
          atomicAdd(out + o + col, acc[mf][nf][r] * wt);  // exactly 2 adds/elem
        }
      }
    }
}

extern "C" void kernel_launch(void* const* d_in, const int* in_sizes, int n_in,
                              void* d_out, int out_size, void* d_ws, size_t ws_size,
                              hipStream_t stream) {
  const float* x   = (const float*)d_in[0];
  const float* rw  = (const float*)d_in[1];
  const float* rb  = (const float*)d_in[2];
  const float* w12 = (const float*)d_in[3];
  const float* w3  = (const float*)d_in[4];
  float* out = (float*)d_out;

  char* ws = (char*)d_ws;
  int*   counts     = (int*)(ws + 0);
  int*   fill       = (int*)(ws + 64);
  int*   base       = (int*)(ws + 128);
  int*   top_i      = (int*)(ws + 4096);
  float* top_w      = (float*)(ws + 4096 + 32768);
  int*   slot_token = (int*)(ws + 4096 + 65536);
  float* slot_wt    = (float*)(ws + 4096 + 98304);
  bf16_t* xb        = (bf16_t*)(ws + 262144);                      // 8 MB
  bf16_t* h         = (bf16_t*)(ws + 262144 + 8388608);            // 33.5 MB
  bf16_t* wT        = (bf16_t*)(ws + 262144 + 8388608 + 33554432); // 67 MB shared:
                                                                   //   w12t during gemm1,
                                                                   //   w3t  during gemm2
  // peak ws usage = 109,314,048 B (~104 MB)

  hipMemsetAsync(d_out, 0, (size_t)out_size * sizeof(float), stream);
  hipMemsetAsync(ws, 0, 256, stream);

  k_xconv<<<dim3(T_TOK * DIM / 4 / 256), dim3(256), 0, stream>>>(x, xb);
  k_wt<<<dim3(64, 16, NE), dim3(256), 0, stream>>>(w12, wT, DIM, 2 * HID);
  k_router<<<dim3(T_TOK / 4), dim3(256), 0, stream>>>(x, rw, rb, counts, top_i, top_w,
                                                      out + (size_t)T_TOK * DIM);
  k_scan<<<dim3(1), dim3(64), 0, stream>>>(counts, base);
  k_gather<<<dim3(T_TOK / 256), dim3(256), 0, stream>>>(top_i, top_w, base, fill,
                                                        slot_token, slot_wt);
  k_gemm1<<<dim3(HID / 64, T_TOK / 128, NE), dim3(256), 0, stream>>>(
      xb, wT, counts, base, slot_token, h);
  // w3t overwrites w12t region (gemm1 done reading it; single stream serializes)
  k_wt<<<dim3(16, 32, NE), dim3(256), 0, stream>>>(w3, wT, HID, DIM);
  k_gemm2<<<dim3(DIM / 128, T_TOK / 128, NE), dim3(256), 0, stream>>>(
      h, wT, counts, base, slot_token, slot_wt, out);
}

// Round 4
// 399.291 us; speedup vs baseline: 2.2043x; 1.0437x over previous
//
#include <hip/hip_runtime.h>
#include <hip/hip_bf16.h>
#include <stdint.h>

typedef __bf16 bf16_t;
typedef __bf16 bf16x8 __attribute__((ext_vector_type(8)));
typedef __bf16 bf16x4 __attribute__((ext_vector_type(4)));
typedef float f32x4 __attribute__((ext_vector_type(4)));

#define T_TOK 4096
#define DIM   1024
#define HID   2048
#define NE    8
#define MAXT  72   // max 128-row m-tiles: 8192/128 + 8

// async global->LDS, 16B per lane, LDS dest = wave-uniform base + lane*16
__device__ __forceinline__ void gload_lds16(const void* g, void* l) {
  __builtin_amdgcn_global_load_lds(
      (const __attribute__((address_space(1))) unsigned int*)g,
      (__attribute__((address_space(3))) unsigned int*)l, 16, 0, 0);
}

// ---------------- weight transpose+convert: in [K][N] f32 -> out [N][K] bf16 ----------------
__global__ __launch_bounds__(256) void k_wt(const float* __restrict__ in,
                                            bf16_t* __restrict__ out,
                                            int K, int N) {
  __shared__ float tile[64][65];
  const size_t eoff = (size_t)blockIdx.z * K * N;
  const int k0 = blockIdx.y * 64, n0 = blockIdx.x * 64;
  const int tid = threadIdx.x;
#pragma unroll
  for (int it = 0; it < 4; ++it) {
    int k = (tid >> 4) + it * 16;
    int n = (tid & 15) * 4;
    float4 v = *(const float4*)(in + eoff + (size_t)(k0 + k) * N + n0 + n);
    tile[k][n] = v.x; tile[k][n + 1] = v.y; tile[k][n + 2] = v.z; tile[k][n + 3] = v.w;
  }
  __syncthreads();
#pragma unroll
  for (int it = 0; it < 2; ++it) {
    int n = (tid >> 3) + it * 32;
    int kc = (tid & 7) * 8;
    bf16x8 o;
#pragma unroll
    for (int j = 0; j < 8; ++j) o[j] = (bf16_t)tile[kc + j][n];
    *(bf16x8*)(out + eoff + (size_t)(n0 + n) * K + k0 + kc) = o;
  }
}

// ---------------- router (+ fused x->bf16): logits, sigmoid, top-2, aux ----------------
__global__ __launch_bounds__(256) void k_router(const float* __restrict__ x,
    const float* __restrict__ rw, const float* __restrict__ rb,
    int* __restrict__ counts, int* __restrict__ top_i, float* __restrict__ top_w,
    float* __restrict__ aux, bf16_t* __restrict__ xb) {
  int t = blockIdx.x * 4 + (threadIdx.x >> 6);
  int lane = threadIdx.x & 63;
  const float* xt = x + (size_t)t * DIM;
  float acc[8] = {0.f,0.f,0.f,0.f,0.f,0.f,0.f,0.f};
#pragma unroll
  for (int it = 0; it < 4; ++it) {
    int i = (it * 64 + lane) * 4;
    float4 xv = *(const float4*)(xt + i);
    bf16x4 o;
    o[0] = (bf16_t)xv.x; o[1] = (bf16_t)xv.y; o[2] = (bf16_t)xv.z; o[3] = (bf16_t)xv.w;
    *(bf16x4*)(xb + (size_t)t * DIM + i) = o;
#pragma unroll
    for (int c = 0; c < 4; ++c) {
      float v = (c == 0) ? xv.x : (c == 1) ? xv.y : (c == 2) ? xv.z : xv.w;
      float4 r0 = *(const float4*)(rw + (size_t)(i + c) * 8);
      float4 r1 = *(const float4*)(rw + (size_t)(i + c) * 8 + 4);
      acc[0] += v * r0.x; acc[1] += v * r0.y; acc[2] += v * r0.z; acc[3] += v * r0.w;
      acc[4] += v * r1.x; acc[5] += v * r1.y; acc[6] += v * r1.z; acc[7] += v * r1.w;
    }
  }
#pragma unroll
  for (int m = 32; m >= 1; m >>= 1) {
#pragma unroll
    for (int e = 0; e < 8; ++e) acc[e] += __shfl_xor(acc[e], m, 64);
  }
  if (lane == 0) {
    float s[8]; float sumsq = 0.f;
#pragma unroll
    for (int e = 0; e < 8; ++e) {
      float lg = acc[e] + rb[e];
      sumsq += lg * lg;
      s[e] = 1.f / (1.f + __expf(-lg));
    }
    int i1 = 0;
#pragma unroll
    for (int e = 1; e < 8; ++e) if (s[e] > s[i1]) i1 = e;
    int i2 = (i1 == 0) ? 1 : 0;
#pragma unroll
    for (int e = 0; e < 8; ++e) if (e != i1 && s[e] > s[i2]) i2 = e;
    float v1 = s[i1], v2 = s[i2];
    float den = v1 + v2 + 1e-6f;
    top_i[2 * t]     = i1; top_i[2 * t + 1] = i2;
    top_w[2 * t]     = v1 / den;
    top_w[2 * t + 1] = v2 / den;
    atomicAdd(&counts[i1], 1);
    atomicAdd(&counts[i2], 1);
    atomicAdd(aux, 0.01f * sumsq * (1.f / 32768.f));
  }
}

// ---------------- plan: base offsets + m-tile table ----------------
__global__ void k_plan(const int* __restrict__ counts, int* __restrict__ base,
                       int* __restrict__ tile_e, int* __restrict__ tile_m0) {
  if (threadIdx.x == 0) {
    int s = 0, nt = 0;
    for (int e = 0; e < NE; ++e) {
      base[e] = s;
      int c = counts[e];
      for (int m0 = 0; m0 < c; m0 += 128) { tile_e[nt] = e; tile_m0[nt] = m0; ++nt; }
      s += c;
    }
    for (; nt < MAXT; ++nt) tile_e[nt] = -1;
  }
}

// ---------------- gather tokens into per-expert slot lists ----------------
__global__ __launch_bounds__(256) void k_gather(const int* __restrict__ top_i,
    const float* __restrict__ top_w, const int* __restrict__ base,
    int* __restrict__ fill, int* __restrict__ slot_token, float* __restrict__ slot_wt,
    int* __restrict__ slot_of) {
  int t = blockIdx.x * 256 + threadIdx.x;
  if (t >= T_TOK) return;
#pragma unroll
  for (int j = 0; j < 2; ++j) {
    int e = top_i[2 * t + j];
    int p = atomicAdd(&fill[e], 1);
    int g = base[e] + p;
    slot_token[g] = t;
    slot_wt[g]    = top_w[2 * t + j];
    slot_of[2 * t + j] = g;
  }
}

// ---------------- GEMM1 + SwiGLU ----------------
// tile 128m x 64n (both W1,W2 panels). 4 waves 2x2. grid = (HID/64, MAXT).
__global__ __launch_bounds__(256) void k_gemm1(
    const bf16_t* __restrict__ xb, const bf16_t* __restrict__ w12t,
    const int* __restrict__ counts, const int* __restrict__ base,
    const int* __restrict__ tile_e, const int* __restrict__ tile_m0,
    const int* __restrict__ slot_token, bf16_t* __restrict__ h) {
  const int e = tile_e[blockIdx.y];
  if (e < 0) return;
  const int m0  = tile_m0[blockIdx.y];
  const int cnt = counts[e];
  const int bas = base[e];
  const int n0 = blockIdx.x * 64;           // hid col base, [0,2048)
  const bf16_t* W1 = w12t + (size_t)e * (4096u * 1024u) + (size_t)n0 * 1024u;
  const bf16_t* W2 = W1 + (size_t)2048 * 1024;

  __shared__ bf16_t sA[128 * 64];
  __shared__ bf16_t sB1[64 * 64];
  __shared__ bf16_t sB2[64 * 64];

  const int tid = threadIdx.x, lane = tid & 63, wid = tid >> 6;
  const int wr = wid >> 1, wc = wid & 1;
  const int lr = lane >> 3, sw = (lane & 7) ^ lr;  // swizzled source chunk

  int tokA[4];
#pragma unroll
  for (int i = 0; i < 4; ++i) {
    int row = m0 + wid * 32 + i * 8 + lr;
    tokA[i] = slot_token[bas + (row < cnt ? row : cnt - 1)];
  }

  f32x4 acc1[4][2] = {};
  f32x4 acc2[4][2] = {};

  for (int k0 = 0; k0 < DIM; k0 += 64) {
#pragma unroll
    for (int i = 0; i < 4; ++i)
      gload_lds16(xb + (size_t)tokA[i] * DIM + k0 + sw * 8,
                  sA + (wid * 32 + i * 8) * 64);
#pragma unroll
    for (int i = 0; i < 2; ++i) {
      int n = wid * 16 + i * 8 + lr;
      gload_lds16(W1 + (size_t)n * 1024 + k0 + sw * 8, sB1 + (wid * 16 + i * 8) * 64);
      gload_lds16(W2 + (size_t)n * 1024 + k0 + sw * 8, sB2 + (wid * 16 + i * 8) * 64);
    }
    __syncthreads();
#pragma unroll
    for (int kk = 0; kk < 2; ++kk) {
      const int g = kk * 4 + (lane >> 4);
      bf16x8 a[4], b1[2], b2[2];
#pragma unroll
      for (int mf = 0; mf < 4; ++mf) {
        int r = wr * 64 + mf * 16 + (lane & 15);
        a[mf] = *(const bf16x8*)(sA + r * 64 + ((g ^ (r & 7)) << 3));
      }
#pragma unroll
      for (int nf = 0; nf < 2; ++nf) {
        int n = wc * 32 + nf * 16 + (lane & 15);
        b1[nf] = *(const bf16x8*)(sB1 + n * 64 + ((g ^ (n & 7)) << 3));
        b2[nf] = *(const bf16x8*)(sB2 + n * 64 + ((g ^ (n & 7)) << 3));
      }
#pragma unroll
      for (int mf = 0; mf < 4; ++mf)
#pragma unroll
        for (int nf = 0; nf < 2; ++nf) {
          acc1[mf][nf] = __builtin_amdgcn_mfma_f32_16x16x32_bf16(a[mf], b1[nf], acc1[mf][nf], 0, 0, 0);
          acc2[mf][nf] = __builtin_amdgcn_mfma_f32_16x16x32_bf16(a[mf], b2[nf], acc2[mf][nf], 0, 0, 0);
        }
    }
    __syncthreads();
  }
#pragma unroll
  for (int mf = 0; mf < 4; ++mf)
#pragma unroll
    for (int r = 0; r < 4; ++r) {
      int m = wr * 64 + mf * 16 + ((lane >> 4) << 2) + r;
      if (m0 + m < cnt) {
        size_t rowoff = (size_t)(bas + m0 + m) * HID + n0;
#pragma unroll
        for (int nf = 0; nf < 2; ++nf) {
          int col = wc * 32 + nf * 16 + (lane & 15);
          float d1 = acc1[mf][nf][r], d2 = acc2[mf][nf][r];
          h[rowoff + col] = (bf16_t)((d1 / (1.f + __expf(-d1))) * d2);
        }
      }
    }
}

// ---------------- GEMM2: eout[slot] = wt * (h @ W3), plain bf16 stores ----------------
// tile 128m x 128n, 4 waves 2x2. grid = (DIM/128, MAXT).
__global__ __launch_bounds__(256) void k_gemm2(
    const bf16_t* __restrict__ h, const bf16_t* __restrict__ w3t,
    const int* __restrict__ counts, const int* __restrict__ base,
    const int* __restrict__ tile_e, const int* __restrict__ tile_m0,
    const float* __restrict__ slot_wt, bf16_t* __restrict__ eout) {
  const int e = tile_e[blockIdx.y];
  if (e < 0) return;
  const int m0  = tile_m0[blockIdx.y];
  const int cnt = counts[e];
  const int bas = base[e];
  const int n0 = blockIdx.x * 128;
  const bf16_t* W = w3t + (size_t)e * (1024u * 2048u);

  __shared__ bf16_t sA[128 * 64];
  __shared__ bf16_t sB[128 * 64];

  const int tid = threadIdx.x, lane = tid & 63, wid = tid >> 6;
  const int wr = wid >> 1, wc = wid & 1;
  const int lr = lane >> 3, sw = (lane & 7) ^ lr;

  int rowA[4];
#pragma unroll
  for (int i = 0; i < 4; ++i) {
    int row = m0 + wid * 32 + i * 8 + lr;
    rowA[i] = bas + (row < cnt ? row : cnt - 1);
  }

  f32x4 acc[4][4] = {};

  for (int k0 = 0; k0 < HID; k0 += 64) {
#pragma unroll
    for (int i = 0; i < 4; ++i) {
      gload_lds16(h + (size_t)rowA[i] * HID + k0 + sw * 8,
                  sA + (wid * 32 + i * 8) * 64);
      int n = wid * 32 + i * 8 + lr;
      gload_lds16(W + (size_t)(n0 + n) * 2048 + k0 + sw * 8,
                  sB + (wid * 32 + i * 8) * 64);
    }
    __syncthreads();
#pragma unroll
    for (int kk = 0; kk < 2; ++kk) {
      const int g = kk * 4 + (lane >> 4);
      bf16x8 a[4], b[4];
#pragma unroll
      for (int mf = 0; mf < 4; ++mf) {
        int r = wr * 64 + mf * 16 + (lane & 15);
        a[mf] = *(const bf16x8*)(sA + r * 64 + ((g ^ (r & 7)) << 3));
      }
#pragma unroll
      for (int nf = 0; nf < 4; ++nf) {
        int n = wc * 64 + nf * 16 + (lane & 15);
        b[nf] = *(const bf16x8*)(sB + n * 64 + ((g ^ (n & 7)) << 3));
      }
#pragma unroll
      for (int mf = 0; mf < 4; ++mf)
#pragma unroll
        for (int nf = 0; nf < 4; ++nf)
          acc[mf][nf] = __builtin_amdgcn_mfma_f32_16x16x32_bf16(a[mf], b[nf], acc[mf][nf], 0, 0, 0);
    }
    __syncthreads();
  }
#pragma unroll
  for (int mf = 0; mf < 4; ++mf)
#pragma unroll
    for (int r = 0; r < 4; ++r) {
      int m = wr * 64 + mf * 16 + ((lane >> 4) << 2) + r;
      if (m0 + m < cnt) {
        int gs = bas + m0 + m;
        float wt = slot_wt[gs];
        size_t o = (size_t)gs * DIM + n0;
#pragma unroll
        for (int nf = 0; nf < 4; ++nf) {
          int col = wc * 64 + nf * 16 + (lane & 15);
          eout[o + col] = (bf16_t)(acc[mf][nf][r] * wt);
        }
      }
    }
}

// ---------------- combine: out[t] = eout[g0] + eout[g1] ----------------
__global__ __launch_bounds__(256) void k_combine(const bf16_t* __restrict__ eout,
    const int* __restrict__ slot_of, float* __restrict__ out) {
  const int t = blockIdx.x;
  const int c = threadIdx.x * 4;
  const int g0 = slot_of[2 * t], g1 = slot_of[2 * t + 1];
  bf16x4 a = *(const bf16x4*)(eout + (size_t)g0 * DIM + c);
  bf16x4 b = *(const bf16x4*)(eout + (size_t)g1 * DIM + c);
  float4 o;
  o.x = (float)a[0] + (float)b[0];
  o.y = (float)a[1] + (float)b[1];
  o.z = (float)a[2] + (float)b[2];
  o.w = (float)a[3] + (float)b[3];
  *(float4*)(out + (size_t)t * DIM + c) = o;
}

extern "C" void kernel_launch(void* const* d_in, const int* in_sizes, int n_in,
                              void* d_out, int out_size, void* d_ws, size_t ws_size,
                              hipStream_t stream) {
  const float* x   = (const float*)d_in[0];
  const float* rw  = (const float*)d_in[1];
  const float* rb  = (const float*)d_in[2];
  const float* w12 = (const float*)d_in[3];
  const float* w3  = (const float*)d_in[4];
  float* out = (float*)d_out;
  float* aux = out + (size_t)T_TOK * DIM;

  char* ws = (char*)d_ws;
  int*   counts     = (int*)(ws + 0);
  int*   fill       = (int*)(ws + 64);
  int*   base       = (int*)(ws + 128);
  int*   top_i      = (int*)(ws + 4096);
  float* top_w      = (float*)(ws + 4096 + 32768);
  int*   slot_token = (int*)(ws + 4096 + 65536);
  float* slot_wt    = (float*)(ws + 4096 + 98304);
  int*   slot_of    = (int*)(ws + 4096 + 131072);
  int*   tile_e     = (int*)(ws + 4096 + 163840);
  int*   tile_m0    = (int*)(ws + 4096 + 164352);
  bf16_t* xb        = (bf16_t*)(ws + 262144);                      // 8 MiB
  bf16_t* h         = (bf16_t*)(ws + 262144 + 8388608);            // 32 MiB
  bf16_t* wT        = (bf16_t*)(ws + 262144 + 8388608 + 33554432); // 64 MiB region:
                                                                   //   w12t (64M) during gemm1
                                                                   //   w3t (32M) + eout(16M) during gemm2
  bf16_t* eout      = (bf16_t*)((char*)wT + 33554432);
  // peak ws usage ≈ 104.3 MiB (same as R3)

  hipMemsetAsync(ws, 0, 256, stream);                 // counts/fill
  hipMemsetAsync(aux, 0, sizeof(float), stream);      // aux accumulator

  k_wt<<<dim3(64, 16, NE), dim3(256), 0, stream>>>(w12, wT, DIM, 2 * HID);
  k_router<<<dim3(T_TOK / 4), dim3(256), 0, stream>>>(x, rw, rb, counts, top_i, top_w,
                                                      aux, xb);
  k_plan<<<dim3(1), dim3(64), 0, stream>>>(counts, base, tile_e, tile_m0);
  k_gather<<<dim3(T_TOK / 256), dim3(256), 0, stream>>>(top_i, top_w, base, fill,
                                                        slot_token, slot_wt, slot_of);
  k_gemm1<<<dim3(HID / 64, MAXT), dim3(256), 0, stream>>>(
      xb, wT, counts, base, tile_e, tile_m0, slot_token, h);
  // w3t overwrites first half of w12t region (gemm1 done reading it)
  k_wt<<<dim3(16, 32, NE), dim3(256), 0, stream>>>(w3, wT, HID, DIM);
  k_gemm2<<<dim3(DIM / 128, MAXT), dim3(256), 0, stream>>>(
      h, wT, counts, base, tile_e, tile_m0, slot_wt, eout);
  k_combine<<<dim3(T_TOK), dim3(256), 0, stream>>>(eout, slot_of, out);
}